// Round 7
// baseline (548.864 us; speedup 1.0000x reference)
//
#include <hip/hip_runtime.h>
#include <math.h>

#define NA     4096
#define HID    1024
#define LN_EPS 1e-5f

typedef short s8   __attribute__((ext_vector_type(8)));
typedef float f32x4 __attribute__((ext_vector_type(4)));

// ---- workspace layout (BYTE offsets), peak ~57 MB ----
#define OFF_XBF   ((size_t)0)              // [4096][1024] bf16, 8 MB
#define OFF_WQT   ((size_t)8<<20)          // 2 MB each
#define OFF_WKT   ((size_t)10<<20)
#define OFF_WVT   ((size_t)12<<20)
#define OFF_QB    ((size_t)14<<20)         // 8 MB (dead after k_retfin)
#define OFF_KB    ((size_t)22<<20)         // 8 MB (dead after k_scores)
#define OFF_VB    ((size_t)30<<20)         // unused this round (kept for layout stability)
#define OFF_KT    ((size_t)38<<20)         // 8 MB (dead after k_ktv)
#define OFF_VT    ((size_t)46<<20)         // 8 MB (dead after k_ret2)
#define OFF_WOT   ((size_t)54<<20)         // 2 MB
#define OFF_M2F   ((size_t)56<<20)         // fp32 [8][128][128], 512 KB
#define OFF_M2B   (OFF_M2F + ((size_t)512<<10))
#define OFF_RMAXD (OFF_M2F + ((size_t)768<<10))
#define OFF_RINVD (OFF_RMAXD + 16384)
#define OFF_RMAXC (OFF_RINVD + 16384)
#define OFF_RINVC (OFF_RMAXC + 16384)
#define OFF_RETF  ((size_t)22<<20)         // fp32 [4096][768], 12 MB; aliases KB+VB[0:4M]
#define OFF_RETB  ((size_t)34<<20)         // bf16 [4096][1024], 8 MB; aliases VB[4:8M]+KT[0:4M]
#define OFF_YF    ((size_t)0)              // fp32 [4096][1024], 16 MB; aliases XBF..QB[0:2M]

__device__ __forceinline__ ushort f2bf(float f) {   // RNE fp32->bf16
    unsigned u = __float_as_uint(f);
    u += 0x7FFFu + ((u >> 16) & 1u);
    return (ushort)(u >> 16);
}

// async 16B global->LDS (per-lane global addr, wave-uniform LDS base + lane*16)
__device__ __forceinline__ void gl16(const void* g, void* l) {
    __builtin_amdgcn_global_load_lds(
        (const __attribute__((address_space(1))) void*)g,
        (__attribute__((address_space(3))) void*)l, 16, 0, 0);
}

// 16 MFMAs on staged [*][32]-linear bf16 tiles; wave (wr,wc) owns 64x64.
__device__ __forceinline__ void mfma_tile(const short* As, const short* Bs,
                                          f32x4 (&acc)[4][4], int lane, int wr, int wc)
{
    const int r = lane & 15, kg = (lane >> 4) * 8;
    s8 a[4], b[4];
#pragma unroll
    for (int i = 0; i < 4; i++) a[i] = *(const s8*)&As[(wr*64 + i*16 + r)*32 + kg];
#pragma unroll
    for (int j = 0; j < 4; j++) b[j] = *(const s8*)&Bs[(wc*64 + j*16 + r)*32 + kg];
#pragma unroll
    for (int i = 0; i < 4; i++)
#pragma unroll
        for (int j = 0; j < 4; j++)
            acc[i][j] = __builtin_amdgcn_mfma_f32_16x16x32_bf16(a[i], b[j], acc[i][j], 0, 0, 0);
}

// Double-buffered NT GEMM (256 thr, 4 waves 2x2). 2-phase pipeline:
// stage(nxt) || MFMA(cur), one barrier/K-step (syncthreads = vmcnt drain AFTER MFMA).
// As/Bs are 2*128*32 shorts.
__device__ __forceinline__ void gemm_bf16_nt_db(const ushort* A, int lda,
    const ushort* Bt, int ldb, int K, int row0, int col0,
    short* As, short* Bs, f32x4 (&acc)[4][4], int tid)
{
    const int lane = tid & 63, wave = tid >> 6, wr = wave >> 1, wc = wave & 1;
    const int srow = wave*32 + (lane >> 2), scol = (lane & 3) * 8;
    const ushort* Ap0 = A  + (size_t)(row0 + srow) * lda + scol;
    const ushort* Ap1 = Ap0 + 16 * (size_t)lda;
    const ushort* Bp0 = Bt + (size_t)(col0 + srow) * ldb + scol;
    const ushort* Bp1 = Bp0 + 16 * (size_t)ldb;
    const int o0 = (wave*32)*32, o1 = o0 + 512;
    gl16(Ap0, As + o0); gl16(Ap1, As + o1);
    gl16(Bp0, Bs + o0); gl16(Bp1, Bs + o1);
    __syncthreads();
    int cur = 0;
    for (int kt = 32; kt < K; kt += 32) {
        const int nb = (cur ^ 1) * 4096;
        gl16(Ap0 + kt, As + nb + o0); gl16(Ap1 + kt, As + nb + o1);
        gl16(Bp0 + kt, Bs + nb + o0); gl16(Bp1 + kt, Bs + nb + o1);
        mfma_tile(As + cur*4096, Bs + cur*4096, acc, lane, wr, wc);
        __syncthreads();
        cur ^= 1;
    }
    mfma_tile(As + cur*4096, Bs + cur*4096, acc, lane, wr, wc);
}

#define ZERO_ACC(acc) { f32x4 z = {0.f,0.f,0.f,0.f}; \
    _Pragma("unroll") for (int i=0;i<4;i++) _Pragma("unroll") for (int j=0;j<4;j++) acc[i][j]=z; }

// =====================================================================
// prep: z=0 X->bf16 ; z=1..4 transpose+convert Wq/Wk/Wv/Wo
// =====================================================================
__global__ __launch_bounds__(256) void k_prep(const float* __restrict__ X,
    const float* __restrict__ Wq, const float* __restrict__ Wk,
    const float* __restrict__ Wv, const float* __restrict__ Wo, char* __restrict__ wsb)
{
    const int z = blockIdx.z, bx = blockIdx.x, by = blockIdx.y, t = threadIdx.x;
    const int lr = t >> 2, jb = t & 3;
    if (z == 0) {
        const float* src = X + (size_t)(by*64 + lr) * HID + bx*64 + jb*16;
        ushort* dst = (ushort*)(wsb + OFF_XBF) + (size_t)(by*64 + lr) * HID + bx*64 + jb*16;
        union { ushort u[16]; uint4 q[2]; } pk;
        union { float f[16]; float4 v[4]; } fa;
#pragma unroll
        for (int m = 0; m < 4; m++) fa.v[m] = ((const float4*)src)[m];
#pragma unroll
        for (int m = 0; m < 16; m++) pk.u[m] = f2bf(fa.f[m]);
        ((uint4*)dst)[0] = pk.q[0]; ((uint4*)dst)[1] = pk.q[1];
        return;
    }
    if (by >= 16) return;
    __shared__ ushort Tl[64][72];
    const float* W = (z == 1) ? Wq : (z == 2) ? Wk : (z == 3) ? Wv : Wo;
    ushort* WT = (ushort*)(wsb + ((z==1)?OFF_WQT:(z==2)?OFF_WKT:(z==3)?OFF_WVT:OFF_WOT));
    const int r0 = by*64, c0 = bx*64;
    const float* src = W + (size_t)(r0 + lr) * HID + c0 + jb*16;
    union { float f[16]; float4 v[4]; } fa;
#pragma unroll
    for (int m = 0; m < 4; m++) fa.v[m] = ((const float4*)src)[m];
#pragma unroll
    for (int m = 0; m < 16; m++) Tl[lr][jb*16 + m] = f2bf(fa.f[m]);
    __syncthreads();
    union { ushort u[16]; uint4 q[2]; } pk;
#pragma unroll
    for (int m = 0; m < 16; m++) pk.u[m] = Tl[jb*16 + m][lr];
    ushort* dst = WT + (size_t)(c0 + lr) * HID + r0 + jb*16;
    ((uint4*)dst)[0] = pk.q[0]; ((uint4*)dst)[1] = pk.q[1];
}

// =====================================================================
// Row softmax stats for f_dist / f_clb
// =====================================================================
__global__ __launch_bounds__(256) void k_rowstats(const float* __restrict__ f_dist,
    const float* __restrict__ f_clb, char* __restrict__ wsb)
{
    const int row = blockIdx.x, mat = blockIdx.y, t = threadIdx.x;
    const float* F = mat ? f_clb : f_dist;
    float* rmax = (float*)(wsb + (mat ? OFF_RMAXC : OFF_RMAXD));
    float* rinv = (float*)(wsb + (mat ? OFF_RINVC : OFF_RINVD));
    float4 v[4];
#pragma unroll
    for (int p = 0; p < 4; p++)
        v[p] = *(const float4*)(F + (size_t)row * NA + 4*t + 1024*p);
    float m = -1e30f;
#pragma unroll
    for (int p = 0; p < 4; p++)
        m = fmaxf(m, fmaxf(fmaxf(v[p].x, v[p].y), fmaxf(v[p].z, v[p].w)));
    for (int off = 32; off; off >>= 1) m = fmaxf(m, __shfl_xor(m, off));
    __shared__ float sb[4];
    if ((t & 63) == 0) sb[t >> 6] = m;
    __syncthreads();
    const float m4 = fmaxf(fmaxf(sb[0], sb[1]), fmaxf(sb[2], sb[3]));
    __syncthreads();
    float s = 0.f;
#pragma unroll
    for (int p = 0; p < 4; p++)
        s += expf(v[p].x-m4) + expf(v[p].y-m4) + expf(v[p].z-m4) + expf(v[p].w-m4);
    for (int off = 32; off; off >>= 1) s += __shfl_xor(s, off);
    if ((t & 63) == 0) sb[t >> 6] = s;
    __syncthreads();
    if (t == 0) { rmax[row] = m4; rinv[row] = 1.0f / (sb[0]+sb[1]+sb[2]+sb[3]); }
}

// =====================================================================
// proj: z=0 Qb, z=1 Kb (A=XBF,Bt=W*T, out [n][d]); z=2 VT directly
//       (A=WVT, Bt=XBF, out [d][n] = Wv^T X^T)
// =====================================================================
__global__ __launch_bounds__(256) void k_proj(char* __restrict__ wsb)
{
    __shared__ __align__(16) short As[2*4096], Bs[2*4096];
    const int z = blockIdx.z;
    const ushort* A; const ushort* Bt; int row0, col0;
    if (z < 2) {
        A  = (const ushort*)(wsb + OFF_XBF);
        Bt = (const ushort*)(wsb + (z ? OFF_WKT : OFF_WQT));
        row0 = blockIdx.y*128; col0 = blockIdx.x*128;
    } else {
        A  = (const ushort*)(wsb + OFF_WVT);
        Bt = (const ushort*)(wsb + OFF_XBF);
        row0 = blockIdx.x*128; col0 = blockIdx.y*128;   // rows=d (8), cols=n (32)
    }
    f32x4 acc[4][4]; ZERO_ACC(acc);
    gemm_bf16_nt_db(A, HID, Bt, HID, HID, row0, col0, As, Bs, acc, threadIdx.x);
    const int lane = threadIdx.x & 63, wave = threadIdx.x >> 6, wr = wave>>1, wc = wave&1;
    if (z < 2) {
        ushort* O = (ushort*)(wsb + (z ? OFF_KB : OFF_QB));
#pragma unroll
        for (int i = 0; i < 4; i++)
#pragma unroll
        for (int e = 0; e < 4; e++) {
            const int r = row0 + wr*64 + i*16 + (lane>>4)*4 + e;
#pragma unroll
            for (int j = 0; j < 4; j++) {
                const int c = col0 + wc*64 + j*16 + (lane & 15);
                O[(size_t)r*HID + c] = f2bf(acc[i][j][e]);
            }
        }
    } else {
        ushort* VT = (ushort*)(wsb + OFF_VT);
#pragma unroll
        for (int i = 0; i < 4; i++)
#pragma unroll
        for (int e = 0; e < 4; e++) {
            const int r = row0 + wr*64 + i*16 + (lane>>4)*4 + e;      // d
#pragma unroll
            for (int j = 0; j < 4; j++) {
                const int c = col0 + wc*64 + j*16 + (lane & 15);      // n
                VT[(size_t)r*NA + c] = f2bf(acc[i][j][e]);
            }
        }
    }
}

// =====================================================================
// transK: Kb -> KT (K only; V transposed directly in k_proj)
// =====================================================================
__global__ __launch_bounds__(256) void k_transK(char* __restrict__ wsb)
{
    const ushort* in = (const ushort*)(wsb + OFF_KB);
    ushort* out = (ushort*)(wsb + OFF_KT);
    const int n0 = blockIdx.y*64, c0 = blockIdx.x*64;
    const int t = threadIdx.x, lr = t >> 2, jb = t & 3;
    __shared__ ushort Tl[64][72];
    const ushort* src = in + (size_t)(n0 + lr) * HID + c0 + jb*16;
    union { ushort u[16]; uint4 q[2]; } pk;
    pk.q[0] = ((const uint4*)src)[0]; pk.q[1] = ((const uint4*)src)[1];
#pragma unroll
    for (int m = 0; m < 16; m++) Tl[lr][jb*16 + m] = pk.u[m];
    __syncthreads();
#pragma unroll
    for (int m = 0; m < 16; m++) pk.u[m] = Tl[jb*16 + m][lr];
    ushort* dst = out + (size_t)(c0 + lr) * NA + n0 + jb*16;
    ((uint4*)dst)[0] = pk.q[0]; ((uint4*)dst)[1] = pk.q[1];
}

// =====================================================================
// ktv: M2[h] = M_h^T = (VT_h)(KT_h)^T, split over 16 n-chunks, atomicAdd fp32
// =====================================================================
__global__ __launch_bounds__(256) void k_ktv(char* __restrict__ wsb)
{
    __shared__ __align__(16) short As[2*4096], Bs[2*4096];
    const int ci = blockIdx.x, h = blockIdx.y;
    const ushort* A  = (const ushort*)(wsb + OFF_VT) + (size_t)h*128*NA + ci*256;
    const ushort* Bt = (const ushort*)(wsb + OFF_KT) + (size_t)h*128*NA + ci*256;
    f32x4 acc[4][4]; ZERO_ACC(acc);
    gemm_bf16_nt_db(A, NA, Bt, NA, 256, 0, 0, As, Bs, acc, threadIdx.x);
    float* M2f = (float*)(wsb + OFF_M2F) + (size_t)h*16384;
    const int lane = threadIdx.x & 63, wave = threadIdx.x >> 6, wr = wave>>1, wc = wave&1;
#pragma unroll
    for (int i = 0; i < 4; i++)
#pragma unroll
    for (int e = 0; e < 4; e++) {
        const int r = wr*64 + i*16 + (lane>>4)*4 + e;
#pragma unroll
        for (int j = 0; j < 4; j++) {
            const int c = wc*64 + j*16 + (lane & 15);
            atomicAdd(&M2f[r*128 + c], acc[i][j][e]);
        }
    }
}

__global__ __launch_bounds__(256) void k_m2cvt(char* __restrict__ wsb)
{
    const int i = (blockIdx.x*256 + threadIdx.x) * 8;
    const float* s = (const float*)(wsb + OFF_M2F);
    ushort* d = (ushort*)(wsb + OFF_M2B);
    union { float f[8]; float4 v[2]; } fa;
    fa.v[0] = *(const float4*)(s + i); fa.v[1] = *(const float4*)(s + i + 4);
    union { ushort u[8]; uint4 q; } pk;
#pragma unroll
    for (int m = 0; m < 8; m++) pk.u[m] = f2bf(fa.f[m]);
    *(uint4*)(d + i) = pk.q;
}

// =====================================================================
// scores: out = c/8 * Qb@Kb^T + c/4 * (adj + softmax(fd) + softmax(fc))
// =====================================================================
__global__ __launch_bounds__(256) void k_scores(char* __restrict__ wsb,
    const float* __restrict__ f_adj, const float* __restrict__ f_dist,
    const float* __restrict__ f_clb, float* __restrict__ outs, float cdiv8, float cdiv4)
{
    __shared__ __align__(16) short As[2*4096], Bs[2*4096];
    const int row0 = blockIdx.y*128, col0 = blockIdx.x*128;
    f32x4 acc[4][4]; ZERO_ACC(acc);
    gemm_bf16_nt_db((const ushort*)(wsb + OFF_QB), HID,
                    (const ushort*)(wsb + OFF_KB), HID, HID, row0, col0,
                    As, Bs, acc, threadIdx.x);
    const float* rmaxd = (const float*)(wsb + OFF_RMAXD);
    const float* rinvd = (const float*)(wsb + OFF_RINVD);
    const float* rmaxc = (const float*)(wsb + OFF_RMAXC);
    const float* rinvc = (const float*)(wsb + OFF_RINVC);
    const int lane = threadIdx.x & 63, wave = threadIdx.x >> 6, wr = wave>>1, wc = wave&1;
#pragma unroll
    for (int i = 0; i < 4; i++)
#pragma unroll
    for (int e = 0; e < 4; e++) {
        const int r = row0 + wr*64 + i*16 + (lane>>4)*4 + e;
        const float rmd = rmaxd[r], rid = rinvd[r], rmc = rmaxc[r], ric = rinvc[r];
#pragma unroll
        for (int j = 0; j < 4; j++) {
            const int c = col0 + wc*64 + j*16 + (lane & 15);
            const size_t idx = (size_t)r * NA + c;
            const float bias = f_adj[idx] + __expf(f_dist[idx]-rmd)*rid
                                          + __expf(f_clb[idx]-rmc)*ric;
            outs[idx] = cdiv8 * acc[i][j][e] + cdiv4 * bias;
        }
    }
}

// =====================================================================
// ret2: RETF[:, p*256..+256) += B_p @ [v_2p | v_2p+1]  (merged head pair,
//       split-K x4, fp32 atomic accum). Double-buffered: F loads + gl16(B)
//       for step t+1 issue before MFMA(t); exp/cvt/ds_write after.
// =====================================================================
__global__ __launch_bounds__(512, 2) void k_ret2(char* __restrict__ wsb,
    const float* __restrict__ f_adj, const float* __restrict__ f_dist,
    const float* __restrict__ f_clb)
{
    __shared__ __align__(16) short As[2*4096];
    __shared__ __align__(16) short Bs[2*8192];
    const int kc = blockIdx.x;            // K chunk 0..3 (1024 each)
    const int row0 = blockIdx.y * 128;
    const int p = blockIdx.z;             // pair 0..2
    const int tid = threadIdx.x, lane = tid & 63, wave = tid >> 6;
    const int wr = wave >> 2, wc = wave & 3;      // 2 x 4 waves over 128x256
    const int ar = tid >> 2, ac = (tid & 3) * 8;  // A reg-stage: 128 rows x 32
    const int srow = wave*32 + (lane >> 2), scol = (lane & 3) * 8;

    const float* F = (p == 0) ? f_adj : (p == 1) ? f_dist : f_clb;
    float rm = 0.f, ri = 1.f;
    if (p) {
        rm = ((const float*)(wsb + ((p==1) ? OFF_RMAXD : OFF_RMAXC)))[row0 + ar];
        ri = ((const float*)(wsb + ((p==1) ? OFF_RINVD : OFF_RINVC)))[row0 + ar];
    }
    const float*  Fp  = F + (size_t)(row0 + ar) * NA + kc*1024 + ac;
    const ushort* Bp0 = (const ushort*)(wsb + OFF_VT) + (size_t)(p*256 + srow) * NA + kc*1024 + scol;
    const ushort* Bp1 = Bp0 + 16 * (size_t)NA;
    const int bo0 = (wave*32)*32, bo1 = bo0 + 512;
    const int aoff = ar*32 + ac;

    f32x4 acc[4][4]; ZERO_ACC(acc);
    // prologue: stage kt=0 into buf 0
    {
        union { float f[8]; float4 v[2]; } fa;
        fa.v[0] = *(const float4*)(Fp);
        fa.v[1] = *(const float4*)(Fp + 4);
        gl16(Bp0, Bs + bo0); gl16(Bp1, Bs + bo1);
        if (p) {
#pragma unroll
            for (int m = 0; m < 8; m++) fa.f[m] = __expf(fa.f[m] - rm) * ri;
        }
        union { ushort u[8]; uint4 q; } pk;
#pragma unroll
        for (int m = 0; m < 8; m++) pk.u[m] = f2bf(fa.f[m]);
        *(uint4*)(As + aoff) = pk.q;
        __syncthreads();
    }
    int cur = 0;
    for (int kt = 32; kt < 1024; kt += 32) {
        const int nxt = cur ^ 1;
        union { float f[8]; float4 v[2]; } fa;      // issue next-tile loads first
        fa.v[0] = *(const float4*)(Fp + kt);
        fa.v[1] = *(const float4*)(Fp + kt + 4);
        gl16(Bp0 + kt, Bs + nxt*8192 + bo0);
        gl16(Bp1 + kt, Bs + nxt*8192 + bo1);
        mfma_tile(As + cur*4096, Bs + cur*8192, acc, lane, wr, wc);   // overlap
        if (p) {
#pragma unroll
            for (int m = 0; m < 8; m++) fa.f[m] = __expf(fa.f[m] - rm) * ri;
        }
        union { ushort u[8]; uint4 q; } pk;
#pragma unroll
        for (int m = 0; m < 8; m++) pk.u[m] = f2bf(fa.f[m]);
        *(uint4*)(As + nxt*4096 + aoff) = pk.q;
        __syncthreads();
        cur = nxt;
    }
    mfma_tile(As + cur*4096, Bs + cur*8192, acc, lane, wr, wc);

    float* RF = (float*)(wsb + OFF_RETF);
#pragma unroll
    for (int i = 0; i < 4; i++)
#pragma unroll
    for (int e = 0; e < 4; e++) {
        const int r = row0 + wr*64 + i*16 + (lane>>4)*4 + e;
#pragma unroll
        for (int j = 0; j < 4; j++) {
            const int c = p*256 + wc*64 + j*16 + (lane & 15);
            atomicAdd(&RF[(size_t)r * 768 + c], acc[i][j][e]);
        }
    }
}

// =====================================================================
// retfin: RETB = relu(c * (q_h @ M_h + RETF[bias part])), bf16 out
// =====================================================================
__global__ __launch_bounds__(256) void k_retfin(char* __restrict__ wsb, float c_scale)
{
    __shared__ __align__(16) short As[2*4096], Bs[2*4096];
    const int h = blockIdx.x, row0 = blockIdx.y * 128;
    const ushort* A  = (const ushort*)(wsb + OFF_QB) + (size_t)row0 * HID + h*128;
    const ushort* Bt = (const ushort*)(wsb + OFF_M2B) + (size_t)h * 16384;
    f32x4 acc[4][4]; ZERO_ACC(acc);
    gemm_bf16_nt_db(A, HID, Bt, 128, 128, 0, 0, As, Bs, acc, threadIdx.x);
    const float* RF = (const float*)(wsb + OFF_RETF);
    ushort* RB = (ushort*)(wsb + OFF_RETB);
    const int lane = threadIdx.x & 63, wave = threadIdx.x >> 6, wr = wave>>1, wc = wave&1;
#pragma unroll
    for (int i = 0; i < 4; i++)
#pragma unroll
    for (int e = 0; e < 4; e++) {
        const int r = row0 + wr*64 + i*16 + (lane>>4)*4 + e;
#pragma unroll
        for (int j = 0; j < 4; j++) {
            const int cl = wc*64 + j*16 + (lane & 15);
            const int col = h*128 + cl;
            float v = acc[i][j][e];
            if (h < 6) v += RF[(size_t)r * 768 + col];
            RB[(size_t)r * HID + col] = f2bf(fmaxf(c_scale * v, 0.f));
        }
    }
}

// =====================================================================
// wo: Yf = X + RETB @ WoT^T + bo
// =====================================================================
__global__ __launch_bounds__(256) void k_wo(char* __restrict__ wsb,
    const float* __restrict__ X, const float* __restrict__ bo)
{
    __shared__ __align__(16) short As[2*4096], Bs[2*4096];
    const int row0 = blockIdx.y*128, col0 = blockIdx.x*128;
    f32x4 acc[4][4]; ZERO_ACC(acc);
    gemm_bf16_nt_db((const ushort*)(wsb + OFF_RETB), HID,
                    (const ushort*)(wsb + OFF_WOT), HID, HID, row0, col0,
                    As, Bs, acc, threadIdx.x);
    float* Y = (float*)(wsb + OFF_YF);
    const int lane = threadIdx.x & 63, wave = threadIdx.x >> 6, wr = wave>>1, wc = wave&1;
#pragma unroll
    for (int i = 0; i < 4; i++)
#pragma unroll
    for (int e = 0; e < 4; e++) {
        const int r = row0 + wr*64 + i*16 + (lane>>4)*4 + e;
#pragma unroll
        for (int j = 0; j < 4; j++) {
            const int c = col0 + wc*64 + j*16 + (lane & 15);
            Y[(size_t)r*HID + c] = acc[i][j][e] + X[(size_t)r*HID + c] + bo[c];
        }
    }
}

// =====================================================================
// LayerNorm rows of Yf -> mol_vec
// =====================================================================
__global__ __launch_bounds__(256) void k_ln(const char* __restrict__ wsb,
    const float* __restrict__ g, const float* __restrict__ b, float* __restrict__ out)
{
    const float* Y = (const float*)(wsb + OFF_YF);
    const int row = blockIdx.x, t = threadIdx.x;
    float4 v = *(const float4*)(Y + (size_t)row * HID + 4*t);
    float s = v.x + v.y + v.z + v.w;
    for (int off = 32; off; off >>= 1) s += __shfl_xor(s, off);
    __shared__ float sb[4];
    if ((t & 63) == 0) sb[t >> 6] = s;
    __syncthreads();
    const float mu = (sb[0]+sb[1]+sb[2]+sb[3]) * (1.0f / HID);
    const float dx = v.x-mu, dy = v.y-mu, dz = v.z-mu, dw = v.w-mu;
    float q = dx*dx + dy*dy + dz*dz + dw*dw;
    __syncthreads();
    for (int off = 32; off; off >>= 1) q += __shfl_xor(q, off);
    if ((t & 63) == 0) sb[t >> 6] = q;
    __syncthreads();
    const float var = (sb[0]+sb[1]+sb[2]+sb[3]) * (1.0f / HID);
    const float rstd = rsqrtf(var + LN_EPS);
    float4 gv = *(const float4*)(g + 4*t);
    float4 bv = *(const float4*)(b + 4*t);
    float4 o = make_float4(dx*rstd*gv.x + bv.x, dy*rstd*gv.y + bv.y,
                           dz*rstd*gv.z + bv.z, dw*rstd*gv.w + bv.w);
    *(float4*)(out + (size_t)row * HID + 4*t) = o;
}

// =====================================================================
extern "C" void kernel_launch(void* const* d_in, const int* in_sizes, int n_in,
                              void* d_out, int out_size, void* d_ws, size_t ws_size,
                              hipStream_t stream)
{
    const float* X      = (const float*)d_in[0];
    const float* f_adj  = (const float*)d_in[1];
    const float* f_dist = (const float*)d_in[2];
    const float* f_clb  = (const float*)d_in[3];
    const float* Wq     = (const float*)d_in[4];
    const float* Wk     = (const float*)d_in[5];
    const float* Wv     = (const float*)d_in[6];
    const float* Wo     = (const float*)d_in[7];
    const float* bo     = (const float*)d_in[8];
    const float* ln_g   = (const float*)d_in[9];
    const float* ln_b   = (const float*)d_in[10];

    char* wsb = (char*)d_ws;
    float* out = (float*)d_out;
    float* out_scores = out + (size_t)NA * HID;

    const float c_scale = (float)pow(1.0 - 1.0/32.0, 1.0 / sqrt(128.0));

    hipMemsetAsync(wsb + OFF_M2F, 0, (size_t)512 << 10, stream);

    k_prep    <<<dim3(16, 64, 5), 256, 0, stream>>>(X, Wq, Wk, Wv, Wo, wsb);
    k_rowstats<<<dim3(NA, 2),     256, 0, stream>>>(f_dist, f_clb, wsb);
    k_proj    <<<dim3(8, 32, 3),  256, 0, stream>>>(wsb);
    k_transK  <<<dim3(16, 64),    256, 0, stream>>>(wsb);
    k_ktv     <<<dim3(16, 8),     256, 0, stream>>>(wsb);
    k_m2cvt   <<<64,              256, 0, stream>>>(wsb);
    k_scores  <<<dim3(32, 32),    256, 0, stream>>>(wsb, f_adj, f_dist, f_clb,
                                                    out_scores, c_scale/8.f, c_scale/4.f);
    // RETF aliases KB (read by k_scores) -> zero it only after k_scores
    hipMemsetAsync(wsb + OFF_RETF, 0, (size_t)NA * 768 * 4, stream);
    k_ret2    <<<dim3(4, 32, 3),  512, 0, stream>>>(wsb, f_adj, f_dist, f_clb);
    k_retfin  <<<dim3(8, 32),     256, 0, stream>>>(wsb, c_scale);
    k_wo      <<<dim3(8, 32),     256, 0, stream>>>(wsb, X, bo);
    k_ln      <<<NA,              256, 0, stream>>>(wsb, ln_g, ln_b, out);
}